// Round 15
// baseline (89.883 us; speedup 1.0000x reference)
//
#include <hip/hip_runtime.h>
#include <hip/hip_bf16.h>

#define BSZ 4096
#define DIM 512
#define NCLS 64
#define MARGIN_F 1.0f
#define NT2 64                       // 64-row tiles per dim
#define NBLK (NT2 * (NT2 + 1) / 2)   // 2080 upper-tri blocks (~8.1/CU)
#define NSL 64                       // 64-col slices (= 64-tiles)
#define NFIN 16                      // finalize blocks
#define BK 64                        // k-bytes per LDS stage (fp8)
#define NKS (DIM / BK)               // 8 stages

typedef float floatx4 __attribute__((ext_vector_type(4)));
typedef unsigned char u8;

// ---------------- workspace layout ----------------
// [0)        : efp8 BSZ*DIM u8 (2 MiB) normalized fp8-e4m3 embeddings
// [OFF_PP)   : part_ps [NSL][BSZ] float (1 MiB) row j vs 64-col tile s
// [OFF_PN)   : part_nm [NSL][BSZ] uint  (1 MiB)
// [OFF_ACC)  : float total; int nv; int counter2
#define OFF_PP  (BSZ * DIM)
#define OFF_PN  (OFF_PP + NSL * BSZ * 4)
#define OFF_ACC (OFF_PN + NSL * BSZ * 4)

__device__ __forceinline__ void gld_lds16(const u8* g, u8* l) {
    __builtin_amdgcn_global_load_lds(
        (const __attribute__((address_space(1))) unsigned int*)g,
        (__attribute__((address_space(3))) unsigned int*)l, 16, 0, 0);
}

// 4 waves/block, one row/wave: L2-normalize, cast fp8-e4m3; init scalars.
__global__ __launch_bounds__(256) void ht_normalize(
        const float* __restrict__ emb, u8* __restrict__ ebf,
        float* __restrict__ acc_total, int* __restrict__ acc_nv,
        int* __restrict__ counter2) {
    const int lane = threadIdx.x & 63;
    const int row = blockIdx.x * 4 + (threadIdx.x >> 6);
    const float4* r4 = (const float4*)(emb + (size_t)row * DIM);
    float4 v0 = r4[lane * 2];
    float4 v1 = r4[lane * 2 + 1];
    float s = v0.x * v0.x + v0.y * v0.y + v0.z * v0.z + v0.w * v0.w
            + v1.x * v1.x + v1.y * v1.y + v1.z * v1.z + v1.w * v1.w;
#pragma unroll
    for (int off = 1; off < 64; off <<= 1) s += __shfl_xor(s, off);
    const float inv = 1.0f / fmaxf(sqrtf(s), 1e-12f);

    int d0 = 0, d1 = 0;
    d0 = __builtin_amdgcn_cvt_pk_fp8_f32(v0.x * inv, v0.y * inv, d0, 0);
    d0 = __builtin_amdgcn_cvt_pk_fp8_f32(v0.z * inv, v0.w * inv, d0, 1);
    d1 = __builtin_amdgcn_cvt_pk_fp8_f32(v1.x * inv, v1.y * inv, d1, 0);
    d1 = __builtin_amdgcn_cvt_pk_fp8_f32(v1.z * inv, v1.w * inv, d1, 1);
    uint2 o; o.x = (unsigned)d0; o.y = (unsigned)d1;
    ((uint2*)(ebf + (size_t)row * DIM))[lane] = o;

    if (blockIdx.x == 0 && threadIdx.x == 0) {
        *acc_total = 0.0f; *acc_nv = 0; *counter2 = 0;
    }
}

// 64x64 fp8 tile per block, upper-tri (by <= bx): 2080 blocks ~8.1/CU.
// Max co-residency (LDS 17.5KB, launch_bounds(256,8) -> 8 blocks/CU) is
// the lever: 8 resident blocks hide each other's barrier/vmcnt drains.
// K-loop: BK=64 (64B rows) = R12's verified swizzle formulas verbatim:
//   staging seg s: row=s>>2, LDS 16B-pos s&3, global granule (s&3)^((s>>3)&3)
//   read: container (h*2+(quad>>1))^((l15>>1)&3), byte off (quad&1)*8
//   -> b64 conflict floor (4 dwords/bank).
// Waves 2x2 (wr,wc in {0,32}), 2x2 accs each.
// Epilogue: row path combines wc-halves via LDS -> part[bx][row0+r] (sole
// writer); col path (offd) combines wr-halves via LDS -> part[by][col0+c]
// (sole writer). Coverage of part[s][j], jt=j>>6: jt<=s row path of (jt,s);
// jt>s col path of (s,jt). Exactly once each -> plain stores, no init.
__global__ __launch_bounds__(256, 8) void ht_gemm_reduce(
        const u8* __restrict__ ebf, const int* __restrict__ labels,
        float* __restrict__ part_ps, unsigned* __restrict__ part_nm) {
    __shared__ u8 sA[2][64 * BK];
    __shared__ u8 sB[2][64 * BK];
    __shared__ int sLI[64];
    __shared__ int sLJ[64];
    __shared__ float sRps[64];
    __shared__ float sRnm[64];
    __shared__ float sCps[64];
    __shared__ float sCnm[64];

    int rem = blockIdx.x, by = 0;
    while (rem >= NT2 - by) { rem -= NT2 - by; ++by; }
    const int bx = by + rem;
    const bool offd = (bx != by);

    const int t = threadIdx.x;
    const int row0 = by * 64;
    const int col0 = bx * 64;

    if (t < 64) sLI[t] = labels[row0 + t];
    else if (t < 128) sLJ[t - 64] = labels[col0 + (t - 64)];

    const int lane = t & 63;
    const int wave = t >> 6;
    const int wr = (wave >> 1) * 32;
    const int wc = (wave & 1) * 32;
    const int l15 = lane & 15;
    const int quad = lane >> 4;

    // staging: 256 16B-segs per array, exactly 1/thread each
    const int sa = t;
    const int ga = (sa & 3) ^ ((sa >> 3) & 3);
    const u8* gA0 = ebf + (size_t)(row0 + (sa >> 2)) * DIM + ga * 16;
    const u8* gB0 = ebf + (size_t)(col0 + (sa >> 2)) * DIM + ga * 16;
    const int lb = wave * 64 * 16;          // wave-uniform LDS byte base

    floatx4 acc[2][2] = {};

    gld_lds16(gA0, &sA[0][lb]);
    gld_lds16(gB0, &sB[0][lb]);

    int cur = 0;
    for (int ks = 0; ks < NKS; ++ks) {
        __syncthreads();  // vmcnt drained: buf[cur] ready; buf[cur^1] reads done
        if (ks + 1 < NKS) {
            const int kb = (ks + 1) * BK;
            gld_lds16(gA0 + kb, &sA[cur ^ 1][lb]);
            gld_lds16(gB0 + kb, &sB[cur ^ 1][lb]);
        }
#pragma unroll
        for (int h = 0; h < 2; ++h) {
            const int co = (((h * 2 + (quad >> 1)) ^ ((l15 >> 1) & 3)) * 16)
                         + (quad & 1) * 8;
            long af[2]; long bf[2];
#pragma unroll
            for (int mi = 0; mi < 2; ++mi)
                af[mi] = *(const long*)(&sA[cur][(wr + mi * 16 + l15) * BK + co]);
#pragma unroll
            for (int ni = 0; ni < 2; ++ni)
                bf[ni] = *(const long*)(&sB[cur][(wc + ni * 16 + l15) * BK + co]);
#pragma unroll
            for (int mi = 0; mi < 2; ++mi)
#pragma unroll
                for (int ni = 0; ni < 2; ++ni)
                    acc[mi][ni] = __builtin_amdgcn_mfma_f32_16x16x32_fp8_fp8(
                        af[mi], bf[ni], acc[mi][ni], 0, 0, 0);
        }
        cur ^= 1;
    }

    // ---- epilogue: C/D layout col=l15, row=quad*4+reg ----
    const float INF = __uint_as_float(0x7F800000u);
    float rowPS[2][4], rowNM[2][4];       // this wave's 32-col row partials
    float colPS[2] = {0.f, 0.f};          // per-ni col partials (8 own rows)
    float colNM[2] = {INF, INF};
#pragma unroll
    for (int mi = 0; mi < 2; ++mi) {
#pragma unroll
        for (int r = 0; r < 4; ++r) {
            const int rloc = wr + mi * 16 + quad * 4 + r;
            const int gi = row0 + rloc;
            const int rl = sLI[rloc];
            float ps = 0.0f, nm = INF;
#pragma unroll
            for (int ni = 0; ni < 2; ++ni) {
                const int cloc = wc + ni * 16 + l15;
                const int gj = col0 + cloc;
                const int cl = sLJ[cloc];
                const float d = __builtin_amdgcn_sqrtf(
                    fmaxf(2.0f - 2.0f * acc[mi][ni][r], 0.0f));
                if (rl == cl) {
                    if (gi != gj) ps += d;      // drop self-pair (diag only)
                    if (offd) colPS[ni] += d;
                } else {
                    nm = fminf(nm, d);
                    if (offd) colNM[ni] = fminf(colNM[ni], d);
                }
            }
#pragma unroll
            for (int off = 1; off < 16; off <<= 1) {
                ps += __shfl_xor(ps, off);
                nm = fminf(nm, __shfl_xor(nm, off));
            }
            rowPS[mi][r] = ps;                  // valid at l15==0
            rowNM[mi][r] = nm;
        }
    }
    // row path: wc==32 waves publish, wc==0 waves combine + store (sole writer)
    if ((wave & 1) && l15 == 0) {
#pragma unroll
        for (int mi = 0; mi < 2; ++mi)
#pragma unroll
            for (int r = 0; r < 4; ++r) {
                const int rloc = wr + mi * 16 + quad * 4 + r;
                sRps[rloc] = rowPS[mi][r];
                sRnm[rloc] = rowNM[mi][r];
            }
    }
    __syncthreads();
    if (!(wave & 1) && l15 == 0) {
#pragma unroll
        for (int mi = 0; mi < 2; ++mi)
#pragma unroll
            for (int r = 0; r < 4; ++r) {
                const int rloc = wr + mi * 16 + quad * 4 + r;
                const int gi = row0 + rloc;
                part_ps[bx * BSZ + gi] = rowPS[mi][r] + sRps[rloc];
                part_nm[bx * BSZ + gi] = __float_as_uint(
                    fminf(rowNM[mi][r], sRnm[rloc]));
            }
    }
    // col path (offd): quad-reduce, wr==32 waves publish, wr==0 combine+store
    if (offd) {
#pragma unroll
        for (int ni = 0; ni < 2; ++ni) {
            colPS[ni] += __shfl_xor(colPS[ni], 16);
            colPS[ni] += __shfl_xor(colPS[ni], 32);
            colNM[ni] = fminf(colNM[ni], __shfl_xor(colNM[ni], 16));
            colNM[ni] = fminf(colNM[ni], __shfl_xor(colNM[ni], 32));
        }
        if (wave >= 2 && quad == 0) {
#pragma unroll
            for (int ni = 0; ni < 2; ++ni) {
                const int cloc = wc + ni * 16 + l15;
                sCps[cloc] = colPS[ni];
                sCnm[cloc] = colNM[ni];
            }
        }
    }
    __syncthreads();
    if (offd && wave < 2 && quad == 0) {
#pragma unroll
        for (int ni = 0; ni < 2; ++ni) {
            const int cloc = wc + ni * 16 + l15;
            const int gj = col0 + cloc;
            part_ps[by * BSZ + gj] = colPS[ni] + sCps[cloc];
            part_nm[by * BSZ + gj] = __float_as_uint(
                fminf(colNM[ni], sCnm[cloc]));
        }
    }
}

// 16 blocks x 256 threads: one row per thread, reduce 64 slices (coalesced).
__global__ __launch_bounds__(256) void ht_finalize(
        const float* __restrict__ part_ps, const unsigned* __restrict__ part_nm,
        const int* __restrict__ labels, float* __restrict__ acc_total,
        int* __restrict__ acc_nv, int* __restrict__ counter2,
        float* __restrict__ out) {
    __shared__ int hist[NCLS];
    __shared__ float sT[4];
    __shared__ int sN[4];
    const int t = threadIdx.x;
    if (t < NCLS) hist[t] = 0;
    __syncthreads();
    for (int i = t; i < BSZ; i += 256) atomicAdd(&hist[labels[i]], 1);
    __syncthreads();

    const int j = blockIdx.x * 256 + t;
    float ps = 0.0f;
    float nm = __uint_as_float(0x7F800000u);
#pragma unroll 8
    for (int s = 0; s < NSL; ++s) {
        ps += part_ps[s * BSZ + j];
        nm = fminf(nm, __uint_as_float(part_nm[s * BSZ + j]));
    }
    const int cnt = hist[labels[j]];
    const int pc = cnt - 1;
    const int nc = BSZ - cnt;
    float loss = 0.0f;
    int lv = 0;
    if (pc > 0 && nc > 0) {
        loss = fmaxf(ps / (float)pc - nm + MARGIN_F, 0.0f);
        lv = 1;
    }
#pragma unroll
    for (int off = 1; off < 64; off <<= 1) {
        loss += __shfl_xor(loss, off);
        lv += __shfl_xor(lv, off);
    }
    if ((t & 63) == 0) { sT[t >> 6] = loss; sN[t >> 6] = lv; }
    __syncthreads();
    if (t == 0) {
        const float tt = sT[0] + sT[1] + sT[2] + sT[3];
        const int nn = sN[0] + sN[1] + sN[2] + sN[3];
        __hip_atomic_fetch_add(acc_total, tt, __ATOMIC_ACQ_REL,
                               __HIP_MEMORY_SCOPE_AGENT);
        __hip_atomic_fetch_add(acc_nv, nn, __ATOMIC_ACQ_REL,
                               __HIP_MEMORY_SCOPE_AGENT);
        const int old2 = __hip_atomic_fetch_add(counter2, 1, __ATOMIC_ACQ_REL,
                                                __HIP_MEMORY_SCOPE_AGENT);
        if (old2 == NFIN - 1) {
            const float ft = __hip_atomic_load(acc_total, __ATOMIC_ACQUIRE,
                                               __HIP_MEMORY_SCOPE_AGENT);
            const int fn = __hip_atomic_load(acc_nv, __ATOMIC_ACQUIRE,
                                             __HIP_MEMORY_SCOPE_AGENT);
            out[0] = (fn > 0) ? ft / (float)fn : 0.0f;
        }
    }
}

extern "C" void kernel_launch(void* const* d_in, const int* in_sizes, int n_in,
                              void* d_out, int out_size, void* d_ws, size_t ws_size,
                              hipStream_t stream) {
    const float* emb = (const float*)d_in[0];
    const int* labels = (const int*)d_in[1];
    float* out = (float*)d_out;
    char* ws = (char*)d_ws;

    u8* ebf = (u8*)ws;
    float* part_ps = (float*)(ws + OFF_PP);
    unsigned* part_nm = (unsigned*)(ws + OFF_PN);
    float* acc_total = (float*)(ws + OFF_ACC);
    int* acc_nv = (int*)(ws + OFF_ACC + 4);
    int* counter2 = (int*)(ws + OFF_ACC + 8);

    ht_normalize<<<BSZ / 4, 256, 0, stream>>>(emb, ebf, acc_total, acc_nv,
                                              counter2);
    ht_gemm_reduce<<<NBLK, 256, 0, stream>>>(ebf, labels, part_ps, part_nm);
    ht_finalize<<<NFIN, 256, 0, stream>>>(part_ps, part_nm, labels,
                                          acc_total, acc_nv, counter2, out);
}

// Round 16
// 86.748 us; speedup vs baseline: 1.0361x; 1.0361x over previous
//
#include <hip/hip_runtime.h>
#include <hip/hip_bf16.h>

#define BSZ 4096
#define DIM 512
#define NCLS 64
#define MARGIN_F 1.0f
#define NT 32                      // 128-tiles per dim
#define NPAIR (NT * (NT + 1) / 2)  // 528 upper-tri pair tiles (by <= bx)
#define NBLK (NPAIR * 2)           // 1056 blocks: 64x128 halves, ~4.1/CU
#define NSL (2 * NT)               // 64-column slices
#define NFIN 16                    // finalize blocks (16*256 = 4096 rows)
#define BK 64                      // k-bytes (=elems) per LDS stage, fp8
#define NKS (DIM / BK)             // 8 stages (vs 16 in bf16)

typedef float floatx4 __attribute__((ext_vector_type(4)));
typedef unsigned char u8;

// ---------------- workspace layout ----------------
// [0)        : efp8 BSZ*DIM u8 (2 MiB) normalized fp8-e4m3 embeddings
// [OFF_PP)   : part_ps [NSL][BSZ] float (1 MiB) row j vs 64-col group s
// [OFF_PN)   : part_nm [NSL][BSZ] uint  (1 MiB) (float bits; dist>=0)
// [OFF_ACC)  : float total; int nv; int counter2
#define OFF_PP  (BSZ * DIM)
#define OFF_PN  (OFF_PP + NSL * BSZ * 4)
#define OFF_ACC (OFF_PN + NSL * BSZ * 4)

// async global->LDS, 16 B/lane; LDS dest = wave-uniform base + lane*16
__device__ __forceinline__ void gld_lds16(const u8* g, u8* l) {
    __builtin_amdgcn_global_load_lds(
        (const __attribute__((address_space(1))) unsigned int*)g,
        (__attribute__((address_space(3))) unsigned int*)l, 16, 0, 0);
}

// 4 waves/block, one row/wave: L2-normalize, cast fp8 e4m3 (OCP, HW cvt);
// init scalar accums.
__global__ __launch_bounds__(256) void ht_normalize(
        const float* __restrict__ emb, u8* __restrict__ ebf,
        float* __restrict__ acc_total, int* __restrict__ acc_nv,
        int* __restrict__ counter2) {
    const int lane = threadIdx.x & 63;
    const int row = blockIdx.x * 4 + (threadIdx.x >> 6);
    const float4* r4 = (const float4*)(emb + (size_t)row * DIM);
    float4 v0 = r4[lane * 2];
    float4 v1 = r4[lane * 2 + 1];
    float s = v0.x * v0.x + v0.y * v0.y + v0.z * v0.z + v0.w * v0.w
            + v1.x * v1.x + v1.y * v1.y + v1.z * v1.z + v1.w * v1.w;
#pragma unroll
    for (int off = 1; off < 64; off <<= 1) s += __shfl_xor(s, off);
    const float inv = 1.0f / fmaxf(sqrtf(s), 1e-12f);

    int d0 = 0, d1 = 0;
    d0 = __builtin_amdgcn_cvt_pk_fp8_f32(v0.x * inv, v0.y * inv, d0, 0);
    d0 = __builtin_amdgcn_cvt_pk_fp8_f32(v0.z * inv, v0.w * inv, d0, 1);
    d1 = __builtin_amdgcn_cvt_pk_fp8_f32(v1.x * inv, v1.y * inv, d1, 0);
    d1 = __builtin_amdgcn_cvt_pk_fp8_f32(v1.z * inv, v1.w * inv, d1, 1);
    uint2 o; o.x = (unsigned)d0; o.y = (unsigned)d1;
    ((uint2*)(ebf + (size_t)row * DIM))[lane] = o;   // bytes lane*8..+7

    if (blockIdx.x == 0 && threadIdx.x == 0) {
        *acc_total = 0.0f; *acc_nv = 0; *counter2 = 0;
    }
}

// 64x128 fp8 tile per block; two blocks (h=0/1) per upper-tri pair (by<=bx).
// BK=64 fp8 = 64 B/row stage = same LDS footprint (24 KB dbuf) and same
// 16B-seg staging pattern as bf16 BK=32 -> 8 drain-rounds at ~4.1 blocks/CU.
// Staging: seg s: row=s>>2, LDS container s&3, global container
// (s&3)^((s>>3)&3) (xor-swizzle inside each row's 64B -> coalescing kept).
// Fragment (mfma_f32_16x16x32_fp8_fp8, k=quad*8+j, 2 halves h per stage):
// ds_read_b64 at container (h*2+(quad>>1))^((l15>>1)&3), half quad&1 ->
// 128 dwords spread exactly 4/bank = b64 conflict-free floor.
// Epilogue partials: exactly one writer per part[s][j] -> plain stores.
__global__ __launch_bounds__(256) void ht_gemm_reduce(
        const u8* __restrict__ ebf, const int* __restrict__ labels,
        float* __restrict__ part_ps, unsigned* __restrict__ part_nm) {
    __shared__ u8 sA[2][64 * BK];
    __shared__ u8 sB[2][128 * BK];
    __shared__ int sLI[64];
    __shared__ int sLJ[128];
    __shared__ float sCPps[128];
    __shared__ float sCPnm[128];

    const int p = blockIdx.x >> 1;       // upper-tri pair index
    const int h2 = blockIdx.x & 1;       // 64-row half of the by-tile
    int rem = p, by = 0;
    while (rem >= NT - by) { rem -= NT - by; ++by; }
    const int bx = by + rem;
    const bool offd = (bx != by);

    const int t = threadIdx.x;
    const int row0 = by * 128 + h2 * 64;
    const int col0 = bx * 128;

    if (t < 64) sLI[t] = labels[row0 + t];
    else if (t < 192) sLJ[t - 64] = labels[col0 + (t - 64)];

    const int lane = t & 63;
    const int wave = t >> 6;
    const int wr = (wave >> 1) * 32;
    const int wc = (wave & 1) * 64;
    const int l15 = lane & 15;
    const int quad = lane >> 4;

    // staging: A 256 segs (1/thread), B 512 segs (2/thread)
    const int sa = t;
    const int ga = (sa & 3) ^ ((sa >> 3) & 3);
    const u8* gA0 = ebf + (size_t)(row0 + (sa >> 2)) * DIM + ga * 16;
    const int sb0 = t, sb1 = 256 + t;
    const int gb0 = (sb0 & 3) ^ ((sb0 >> 3) & 3);
    const int gb1 = (sb1 & 3) ^ ((sb1 >> 3) & 3);
    const u8* gB0 = ebf + (size_t)(col0 + (sb0 >> 2)) * DIM + gb0 * 16;
    const u8* gB1 = ebf + (size_t)(col0 + (sb1 >> 2)) * DIM + gb1 * 16;
    const int lbA = wave * 64 * 16;         // wave-uniform LDS byte bases
    const int lbB0 = wave * 64 * 16;
    const int lbB1 = (256 + wave * 64) * 16;

    floatx4 acc[2][4] = {};

    gld_lds16(gA0, &sA[0][lbA]);
    gld_lds16(gB0, &sB[0][lbB0]);
    gld_lds16(gB1, &sB[0][lbB1]);

    int cur = 0;
    for (int ks = 0; ks < NKS; ++ks) {
        __syncthreads();  // vmcnt drained: buf[cur] ready; buf[cur^1] reads done
        if (ks + 1 < NKS) {
            const int kb = (ks + 1) * BK;
            gld_lds16(gA0 + kb, &sA[cur ^ 1][lbA]);
            gld_lds16(gB0 + kb, &sB[cur ^ 1][lbB0]);
            gld_lds16(gB1 + kb, &sB[cur ^ 1][lbB1]);
        }
#pragma unroll
        for (int h = 0; h < 2; ++h) {
            // swizzled container + 8B half within it
            const int co = (((h * 2 + (quad >> 1)) ^ ((l15 >> 1) & 3)) * 16)
                         + (quad & 1) * 8;
            long af[2]; long bf[4];
#pragma unroll
            for (int mi = 0; mi < 2; ++mi)
                af[mi] = *(const long*)(&sA[cur][(wr + mi * 16 + l15) * BK + co]);
#pragma unroll
            for (int ni = 0; ni < 4; ++ni)
                bf[ni] = *(const long*)(&sB[cur][(wc + ni * 16 + l15) * BK + co]);
#pragma unroll
            for (int mi = 0; mi < 2; ++mi)
#pragma unroll
                for (int ni = 0; ni < 4; ++ni)
                    acc[mi][ni] = __builtin_amdgcn_mfma_f32_16x16x32_fp8_fp8(
                        af[mi], bf[ni], acc[mi][ni], 0, 0, 0);
        }
        cur ^= 1;
    }

    // epilogue: C/D layout col=l15, row=quad*4+reg (shape-determined, m121+)
    const float INF = __uint_as_float(0x7F800000u);
    const int rslice = 2 * bx + (wc >> 6);
    float psc[4] = {0.f, 0.f, 0.f, 0.f};
    float nmc[4] = {INF, INF, INF, INF};
#pragma unroll
    for (int mi = 0; mi < 2; ++mi) {
        const int rbase = wr + mi * 16 + quad * 4;
#pragma unroll
        for (int r = 0; r < 4; ++r) {
            const int rloc = rbase + r;
            const int gi = row0 + rloc;
            const int rl = sLI[rloc];
            float ps = 0.0f, nm = INF;
#pragma unroll
            for (int ni = 0; ni < 4; ++ni) {
                const int cloc = wc + ni * 16 + l15;
                const int gj = col0 + cloc;
                const int cl = sLJ[cloc];
                const float d = __builtin_amdgcn_sqrtf(
                    fmaxf(2.0f - 2.0f * acc[mi][ni][r], 0.0f));
                if (rl == cl) {
                    if (gi != gj) ps += d;      // drop self-pair (diag only)
                    if (offd) psc[ni] += d;
                } else {
                    nm = fminf(nm, d);
                    if (offd) nmc[ni] = fminf(nmc[ni], d);
                }
            }
#pragma unroll
            for (int off = 1; off < 16; off <<= 1) {
                ps += __shfl_xor(ps, off);
                nm = fminf(nm, __shfl_xor(nm, off));
            }
            if (l15 == 0) {                 // sole writer of (rslice, gi)
                part_ps[rslice * BSZ + gi] = ps;
                part_nm[rslice * BSZ + gi] = __float_as_uint(nm);
            }
        }
    }
    if (offd) {
        // col stats for slice 2*by+h2: reduce across quads, combine the two
        // wr-half waves via LDS, wr==0 wave does the single plain store.
        const int cslice = 2 * by + h2;
        float cps[4], cnm[4];
#pragma unroll
        for (int ni = 0; ni < 4; ++ni) {
            float ps = psc[ni], nm = nmc[ni];
            ps += __shfl_xor(ps, 16); ps += __shfl_xor(ps, 32);
            nm = fminf(nm, __shfl_xor(nm, 16));
            nm = fminf(nm, __shfl_xor(nm, 32));
            cps[ni] = ps; cnm[ni] = nm;
        }
        if (wave >= 2 && quad == 0) {       // wr==32 waves publish
#pragma unroll
            for (int ni = 0; ni < 4; ++ni) {
                const int cl = wc + ni * 16 + l15;
                sCPps[cl] = cps[ni];
                sCPnm[cl] = cnm[ni];
            }
        }
        __syncthreads();
        if (wave < 2 && quad == 0) {        // wr==0 waves combine + store
#pragma unroll
            for (int ni = 0; ni < 4; ++ni) {
                const int cl = wc + ni * 16 + l15;
                const int gj = col0 + cl;
                const float ps = cps[ni] + sCPps[cl];
                const float nm = fminf(cnm[ni], sCPnm[cl]);
                part_ps[cslice * BSZ + gj] = ps;
                part_nm[cslice * BSZ + gj] = __float_as_uint(nm);
            }
        }
    }
}

// 16 blocks x 256 threads: one row per thread. Reduce 64 slices (coalesced),
// per-block loss partials -> 2 device atomics per block; last block writes out.
__global__ __launch_bounds__(256) void ht_finalize(
        const float* __restrict__ part_ps, const unsigned* __restrict__ part_nm,
        const int* __restrict__ labels, float* __restrict__ acc_total,
        int* __restrict__ acc_nv, int* __restrict__ counter2,
        float* __restrict__ out) {
    __shared__ int hist[NCLS];
    __shared__ float sT[4];
    __shared__ int sN[4];
    const int t = threadIdx.x;
    if (t < NCLS) hist[t] = 0;
    __syncthreads();
    for (int i = t; i < BSZ; i += 256) atomicAdd(&hist[labels[i]], 1);
    __syncthreads();

    const int j = blockIdx.x * 256 + t;
    float ps = 0.0f;
    float nm = __uint_as_float(0x7F800000u);
#pragma unroll 8
    for (int s = 0; s < NSL; ++s) {
        ps += part_ps[s * BSZ + j];
        nm = fminf(nm, __uint_as_float(part_nm[s * BSZ + j]));
    }
    const int cnt = hist[labels[j]];
    const int pc = cnt - 1;
    const int nc = BSZ - cnt;
    float loss = 0.0f;
    int lv = 0;
    if (pc > 0 && nc > 0) {
        loss = fmaxf(ps / (float)pc - nm + MARGIN_F, 0.0f);
        lv = 1;
    }
#pragma unroll
    for (int off = 1; off < 64; off <<= 1) {
        loss += __shfl_xor(loss, off);
        lv += __shfl_xor(lv, off);
    }
    if ((t & 63) == 0) { sT[t >> 6] = loss; sN[t >> 6] = lv; }
    __syncthreads();
    if (t == 0) {
        const float tt = sT[0] + sT[1] + sT[2] + sT[3];
        const int nn = sN[0] + sN[1] + sN[2] + sN[3];
        __hip_atomic_fetch_add(acc_total, tt, __ATOMIC_ACQ_REL,
                               __HIP_MEMORY_SCOPE_AGENT);
        __hip_atomic_fetch_add(acc_nv, nn, __ATOMIC_ACQ_REL,
                               __HIP_MEMORY_SCOPE_AGENT);
        const int old2 = __hip_atomic_fetch_add(counter2, 1, __ATOMIC_ACQ_REL,
                                                __HIP_MEMORY_SCOPE_AGENT);
        if (old2 == NFIN - 1) {
            const float ft = __hip_atomic_load(acc_total, __ATOMIC_ACQUIRE,
                                               __HIP_MEMORY_SCOPE_AGENT);
            const int fn = __hip_atomic_load(acc_nv, __ATOMIC_ACQUIRE,
                                             __HIP_MEMORY_SCOPE_AGENT);
            out[0] = (fn > 0) ? ft / (float)fn : 0.0f;
        }
    }
}

extern "C" void kernel_launch(void* const* d_in, const int* in_sizes, int n_in,
                              void* d_out, int out_size, void* d_ws, size_t ws_size,
                              hipStream_t stream) {
    const float* emb = (const float*)d_in[0];
    const int* labels = (const int*)d_in[1];
    float* out = (float*)d_out;
    char* ws = (char*)d_ws;

    u8* ebf = (u8*)ws;
    float* part_ps = (float*)(ws + OFF_PP);
    unsigned* part_nm = (unsigned*)(ws + OFF_PN);
    float* acc_total = (float*)(ws + OFF_ACC);
    int* acc_nv = (int*)(ws + OFF_ACC + 4);
    int* counter2 = (int*)(ws + OFF_ACC + 8);

    ht_normalize<<<BSZ / 4, 256, 0, stream>>>(emb, ebf, acc_total, acc_nv,
                                              counter2);
    ht_gemm_reduce<<<NBLK, 256, 0, stream>>>(ebf, labels, part_ps, part_nm);
    ht_finalize<<<NFIN, 256, 0, stream>>>(part_ps, part_nm, labels,
                                          acc_total, acc_nv, counter2, out);
}